// Round 6
// baseline (141.794 us; speedup 1.0000x reference)
//
#include <hip/hip_runtime.h>
#include <hip/hip_bf16.h>

// Problem shape (fixed by setup_inputs): B=2, H=8, T=1024, P=64
#define TDIM 1024
#define PDIM 64
#define BHN  16     // B*H
#define NCH  64     // chunks along T
#define CHS  16     // chunk size (NCH*CHS == TDIM)
#define MAGIC 0x5A5A1234u   // != 0xAAAAAAAA poison

typedef __bf16 bf16_t;
typedef bf16_t bf16x8 __attribute__((ext_vector_type(8)));
typedef float  floatx4 __attribute__((ext_vector_type(4)));

__device__ __forceinline__ floatx4 mfma16(bf16x8 a, bf16x8 b, floatx4 c) {
    return __builtin_amdgcn_mfma_f32_16x16x32_bf16(a, b, c, 0, 0, 0);
}

// ---------------------------------------------------------------------------
// Fused A: per-chunk stats + flag publish + spin + seeded scan.
// grid = BHN*NCH = 1024 blocks of 64 threads (lane = p); 1 wave/block, whole
// grid co-resident (4 waves/CU) -> flag spin cannot deadlock. Flags start as
// 0xAA poison (!= MAGIC) every replay; release store via agent-scope atomic
// (block == wave, so the wave's vmcnt drain orders all lanes' data stores
// before lane 0's flag store). Emits:
//   W[bh][t][p]  = bf16( exp(Q - m_cum) )        (natural layout)
//   U[bh][t][p]  = bf16( V * exp(K) )            (natural layout)
//   Kft[bh][q][t]= bf16( exp(K[t][q]) )          (TRANSPOSED, via LDS tile)
//   den[bh][t]   = fp32 sum_p W*S2cum            (post-loop LDS reduce)
// ---------------------------------------------------------------------------
__global__ __launch_bounds__(64) void scanfeat_kernel(
        const float* __restrict__ Q, const float* __restrict__ K,
        const float* __restrict__ V,
        float* __restrict__ cmax, float* __restrict__ csum,
        unsigned* __restrict__ flags,
        bf16_t* __restrict__ W, bf16_t* __restrict__ U,
        bf16_t* __restrict__ Kft, float* __restrict__ den) {
    int bh = blockIdx.x >> 6;
    int c  = blockIdx.x & 63;
    int p  = threadIdx.x;
    size_t base = (size_t)bh * TDIM * PDIM;
    int t0 = c * CHS;

    // ---- load own chunk (needed for both stats and scan) ----
    float kq[CHS], qq_[CHS], vv[CHS];
#pragma unroll
    for (int i = 0; i < CHS; ++i) {
        kq[i]  = K[base + (size_t)(t0 + i) * PDIM + p];
        qq_[i] = Q[base + (size_t)(t0 + i) * PDIM + p];
        vv[i]  = V[base + (size_t)(t0 + i) * PDIM + p];
    }

    // ---- chunk stats: max(K), sum(exp(2K)); keep exp(K) for later ----
    float ek[CHS];
    float cm = -INFINITY, cs = 0.f;
#pragma unroll
    for (int i = 0; i < CHS; ++i) {
        cm = fmaxf(cm, kq[i]);
        float e = __expf(kq[i]);
        ek[i] = e;
        cs += e * e;
    }
    cmax[(bh * NCH + c) * PDIM + p] = cm;
    csum[(bh * NCH + c) * PDIM + p] = cs;
    __threadfence();                       // device-scope: data before flag
    if (p == 0)
        __hip_atomic_store(&flags[bh * NCH + c], MAGIC,
                           __ATOMIC_RELEASE, __HIP_MEMORY_SCOPE_AGENT);

    // ---- wait for all predecessor chunks' stats (lane p polls flag p) ----
    if (c > 0) {
        if (p < c) {
            while (__hip_atomic_load(&flags[bh * NCH + p],
                                     __ATOMIC_ACQUIRE,
                                     __HIP_MEMORY_SCOPE_AGENT) != MAGIC) { }
        }
        __threadfence();                   // acquire: invalidate stale lines
    }

    // ---- prefix reduction over predecessor chunks ----
    float m = -INFINITY, s = 0.f;
#pragma unroll 8
    for (int cc = 0; cc < c; ++cc) {
        m = fmaxf(m, cmax[(bh * NCH + cc) * PDIM + p]);
        s += csum[(bh * NCH + cc) * PDIM + p];
    }

    __shared__ bf16_t ek_t[CHS][PDIM + 4];   // [t_local][p]
    __shared__ float  dt[CHS][PDIM + 1];     // per-(t,p) den contribution

#pragma unroll
    for (int i = 0; i < CHS; ++i) {
        int t = t0 + i;
        m = fmaxf(m, kq[i]);
        s += ek[i] * ek[i];                   // inclusive running sum exp(2K)
        float w = __expf(qq_[i] - m);         // inclusive running max
        W[base + (size_t)t * PDIM + p] = (bf16_t)w;
        U[base + (size_t)t * PDIM + p] = (bf16_t)(vv[i] * ek[i]);
        ek_t[i][p] = (bf16_t)ek[i];
        dt[i][p] = w * s;
    }
    __syncthreads();

    // den reduce: lane l -> t = l>>2, g = l&3; partial over p = 4*i+g
    {
        int tl = p >> 2, g = p & 3;
        float d = 0.f;
#pragma unroll
        for (int i = 0; i < 16; ++i) d += dt[tl][i * 4 + g];
        d += __shfl_xor(d, 1);
        d += __shfl_xor(d, 2);
        if (g == 0) den[bh * TDIM + t0 + tl] = d;
    }

    // transposed Kft write
    {
        int hi = p >> 4, tl = p & 15;
#pragma unroll
        for (int it = 0; it < 16; ++it) {
            int q = it * 4 + hi;
            Kft[((size_t)bh * PDIM + q) * TDIM + t0 + tl] = ek_t[tl][q];
        }
    }
}

// ---------------------------------------------------------------------------
// B: per-(bh, 64-row tile) causal double matmul — LDS-staged + pipelined.
// 512 thr / 8 waves: wave = par*4 + sub. sub = 16-row substrip of the i-tile,
// par = kt parity. Each super-iteration stages TWO kt tiles (slots 0/1) into
// LDS once (coalesced 128B segments, shared by all waves), while the NEXT
// super-iteration's tiles are register-prefetched so global latency hides
// under the 32 MFMAs of compute. Ct (per-wave C round-trip) and Yred
// (cross-parity reduce) share one LDS buffer, barrier-ordered.
// grid = i*16 + bh (256 blocks); bh&7 spreads XCDs, 2 bh/XCD fits L2.
// ---------------------------------------------------------------------------
__global__ __launch_bounds__(512) void attn_kernel(
        const bf16_t* __restrict__ W, const bf16_t* __restrict__ U,
        const bf16_t* __restrict__ Kft, const float* __restrict__ den,
        float* __restrict__ out) {
    int bh  = blockIdx.x & 15;
    int i   = blockIdx.x >> 4;   // row tile index 0..15
    int tid = threadIdx.x;
    int wave = tid >> 6, lane = tid & 63;
    int lq = lane & 15, qd = lane >> 4;
    int sub = wave & 3;          // substrip: rows [16*sub, 16*sub+16) of tile
    int par = wave >> 2;         // kt parity handled by this wave
    int b = bh >> 3, h = bh & 7;

    __shared__ bf16_t Wt[64][72];
    __shared__ bf16_t Ut[2][64][72];
    __shared__ bf16_t Kt[2][64][72];
    __shared__ __align__(16) char ctyraw[8 * 16 * 72 * 2];  // Ct / Yred union
    __shared__ float denb[64];
    bf16_t (*Ct)[16][72]  = (bf16_t (*)[16][72])ctyraw;
    float  (*Yred)[16][68] = (float (*)[16][68])ctyraw;

    size_t base = (size_t)bh * TDIM * PDIM;
    size_t kftb = (size_t)bh * PDIM * TDIM;
    int row = tid >> 3, c8 = (tid & 7) << 3;   // staging coords: 1 int4/thread

    // ---- stage Wt + denb; prefetch tiles kt=0,1 (always in-bounds) ----
    int4 wfrag = *(const int4*)(W + base + (size_t)(i * 64 + row) * PDIM + c8);
    int4 pu0 = *(const int4*)(U + base + (size_t)(0 * 64 + row) * PDIM + c8);
    int4 pk0 = *(const int4*)(Kft + kftb + (size_t)row * TDIM + 0 * 64 + c8);
    int4 pu1 = *(const int4*)(U + base + (size_t)(1 * 64 + row) * PDIM + c8);
    int4 pk1 = *(const int4*)(Kft + kftb + (size_t)row * TDIM + 1 * 64 + c8);
    *(int4*)&Wt[row][c8] = wfrag;
    if (tid < 64) denb[tid] = den[bh * TDIM + i * 64 + tid];
    __syncthreads();

    // hoist this wave's W A-fragments (rows sub*16+lq of the i-tile)
    bf16x8 a0 = *(const bf16x8*)&Wt[sub * 16 + lq][qd * 8];
    bf16x8 a1 = *(const bf16x8*)&Wt[sub * 16 + lq][32 + qd * 8];

    floatx4 acc[4];
#pragma unroll
    for (int j = 0; j < 4; ++j) acc[j] = (floatx4){0.f, 0.f, 0.f, 0.f};

    int niter = (i >> 1) + 1;
    for (int kt2 = 0; kt2 < niter; ++kt2) {
        __syncthreads();   // previous compute done reading Ut/Kt
        *(int4*)&Ut[0][row][c8] = pu0;
        *(int4*)&Kt[0][row][c8] = pk0;
        *(int4*)&Ut[1][row][c8] = pu1;
        *(int4*)&Kt[1][row][c8] = pk1;
        // prefetch next super-iteration (loads fly under this one's compute)
        if (kt2 + 1 < niter) {
            int ktn = 2 * kt2 + 2;
            int ktn1 = ktn + 1 > 15 ? 15 : ktn + 1;
            pu0 = *(const int4*)(U + base + (size_t)(ktn * 64 + row) * PDIM + c8);
            pk0 = *(const int4*)(Kft + kftb + (size_t)row * TDIM + ktn * 64 + c8);
            pu1 = *(const int4*)(U + base + (size_t)(ktn1 * 64 + row) * PDIM + c8);
            pk1 = *(const int4*)(Kft + kftb + (size_t)row * TDIM + ktn1 * 64 + c8);
        }
        __syncthreads();   // LDS tiles ready

        int kt = 2 * kt2 + par;
        if (kt <= i) {     // wave-uniform
            // ---- phase 1: C[16 x 64] = W_sub . U_tile^T ----
            floatx4 cc[4];
#pragma unroll
            for (int j = 0; j < 4; ++j) {
                bf16x8 b0 = *(const bf16x8*)&Ut[par][j * 16 + lq][qd * 8];
                bf16x8 b1 = *(const bf16x8*)&Ut[par][j * 16 + lq][32 + qd * 8];
                floatx4 t = (floatx4){0.f, 0.f, 0.f, 0.f};
                t = mfma16(a0, b0, t);
                t = mfma16(a1, b1, t);
                cc[j] = t;
            }
            // ---- causal mask + C -> per-wave LDS (C/D: row=qd*4+r, col=lq)
            int trow0 = i * 64 + sub * 16;
#pragma unroll
            for (int j = 0; j < 4; ++j) {
#pragma unroll
                for (int r = 0; r < 4; ++r) {
                    float v = cc[j][r];
                    if (kt == i && (kt * 64 + j * 16 + lq) > (trow0 + qd * 4 + r))
                        v = 0.f;
                    Ct[wave][qd * 4 + r][j * 16 + lq] = (bf16_t)v;
                }
            }
            // same-wave write->read: compiler lgkmcnt, no barrier
            bf16x8 ca0 = *(const bf16x8*)&Ct[wave][lq][qd * 8];
            bf16x8 ca1 = *(const bf16x8*)&Ct[wave][lq][32 + qd * 8];
            // ---- phase 2: Y_sub += C . Kf_tile ----
#pragma unroll
            for (int j = 0; j < 4; ++j) {
                bf16x8 kb0 = *(const bf16x8*)&Kt[par][j * 16 + lq][qd * 8];
                bf16x8 kb1 = *(const bf16x8*)&Kt[par][j * 16 + lq][32 + qd * 8];
                acc[j] = mfma16(ca0, kb0, acc[j]);
                acc[j] = mfma16(ca1, kb1, acc[j]);
            }
        }
    }

    // ---- cross-parity reduce (Yred aliases Ct; barriers order it) ----
    __syncthreads();
    if (par == 1) {
#pragma unroll
        for (int j = 0; j < 4; ++j)
#pragma unroll
            for (int r = 0; r < 4; ++r)
                Yred[sub][qd * 4 + r][j * 16 + lq] = acc[j][r];
    }
    __syncthreads();
    if (par == 0) {
#pragma unroll
        for (int j = 0; j < 4; ++j) {
#pragma unroll
            for (int r = 0; r < 4; ++r) {
                int trow_l = sub * 16 + qd * 4 + r;
                int tg = i * 64 + trow_l;
                float y = acc[j][r] + Yred[sub][qd * 4 + r][j * 16 + lq];
                y = y / (denb[trow_l] + 1e-6f);
                out[((size_t)b * TDIM + tg) * (8 * PDIM) + h * PDIM + j * 16 + lq] = y;
            }
        }
    }
}

// ---------------------------------------------------------------------------
extern "C" void kernel_launch(void* const* d_in, const int* in_sizes, int n_in,
                              void* d_out, int out_size, void* d_ws, size_t ws_size,
                              hipStream_t stream) {
    const float* Q = (const float*)d_in[0];
    const float* K = (const float*)d_in[1];
    const float* V = (const float*)d_in[2];
    float* out = (float*)d_out;

    bf16_t* Wf   = (bf16_t*)d_ws;                       // 2 MB
    bf16_t* Uf   = Wf + (size_t)BHN * TDIM * PDIM;      // 2 MB
    bf16_t* Kft  = Uf + (size_t)BHN * TDIM * PDIM;      // 2 MB
    float*  den  = (float*)(Kft + (size_t)BHN * TDIM * PDIM);  // 64 KB
    float*  cmax = den + (size_t)BHN * TDIM;            // 256 KB
    float*  csum = cmax + (size_t)BHN * NCH * PDIM;     // 256 KB
    unsigned* flags = (unsigned*)(csum + (size_t)BHN * NCH * PDIM);  // 4 KB
    // flags start at 0xAAAAAAAA (harness poison) every call; != MAGIC.

    scanfeat_kernel<<<BHN * NCH, 64, 0, stream>>>(Q, K, V, cmax, csum, flags,
                                                  Wf, Uf, Kft, den);
    attn_kernel<<<256, 512, 0, stream>>>(Wf, Uf, Kft, den, out);
}

// Round 7
// 101.787 us; speedup vs baseline: 1.3930x; 1.3930x over previous
//
#include <hip/hip_runtime.h>
#include <hip/hip_bf16.h>

// Problem shape (fixed by setup_inputs): B=2, H=8, T=1024, P=64
#define TDIM 1024
#define PDIM 64
#define BHN  16     // B*H
#define NCH  64     // chunks along T
#define CHS  16     // chunk size (NCH*CHS == TDIM)

typedef __bf16 bf16_t;
typedef bf16_t bf16x8 __attribute__((ext_vector_type(8)));
typedef float  floatx4 __attribute__((ext_vector_type(4)));

__device__ __forceinline__ floatx4 mfma16(bf16x8 a, bf16x8 b, floatx4 c) {
    return __builtin_amdgcn_mfma_f32_16x16x32_bf16(a, b, c, 0, 0, 0);
}

// ---------------------------------------------------------------------------
// Fused A (sync-free): each block recomputes its chunk-prefix (max K, sum
// exp(2K)) DIRECTLY from K instead of consuming another kernel's stats.
// R6 lesson: cross-XCD producer->consumer flag sync stalled 73 us (stale-L2
// polling / fence L2-maintenance); recomputing from L2-hot K is ~2 us.
// grid: g = c*16 + bh  (1024 blocks of 64 thr, lane = p). With round-robin
// dispatch XCD = g&7 = bh&7, so each bh's 64 blocks share one XCD and K's
// 256 KB/bh working set stays L2-resident (2 bh -> 512 KB per XCD).
// Emits:
//   W[bh][t][p]  = bf16( exp(Q - m_cum) )        (natural layout)
//   U[bh][t][p]  = bf16( V * exp(K) )            (natural layout)
//   Kft[bh][q][t]= bf16( exp(K[t][q]) )          (TRANSPOSED, via LDS tile)
//   den[bh][t]   = fp32 sum_p W*S2cum            (post-loop LDS reduce)
// ---------------------------------------------------------------------------
__global__ __launch_bounds__(64) void scanfeat_kernel(
        const float* __restrict__ Q, const float* __restrict__ K,
        const float* __restrict__ V,
        bf16_t* __restrict__ W, bf16_t* __restrict__ U,
        bf16_t* __restrict__ Kft, float* __restrict__ den) {
    int g  = blockIdx.x;
    int bh = g & 15;
    int c  = g >> 4;
    int p  = threadIdx.x;
    size_t base = (size_t)bh * TDIM * PDIM;
    int t0 = c * CHS;

    // ---- own chunk loads issued first (in flight under the prefix loop) ----
    float kq[CHS], qq_[CHS], vv[CHS];
#pragma unroll
    for (int i = 0; i < CHS; ++i) {
        kq[i]  = K[base + (size_t)(t0 + i) * PDIM + p];
        qq_[i] = Q[base + (size_t)(t0 + i) * PDIM + p];
        vv[i]  = V[base + (size_t)(t0 + i) * PDIM + p];
    }

    // ---- prefix over all rows t < t0: running max(K), sum(exp(2K)) ----
    // 4-way split accumulators break the dependent fmax/fma chains; loads
    // are column-p dwords, 256 B coalesced per row, L2-resident per XCD.
    const float* Kb = K + base + p;
    float m0 = -INFINITY, m1 = -INFINITY, m2 = -INFINITY, m3 = -INFINITY;
    float s0 = 0.f, s1 = 0.f, s2 = 0.f, s3 = 0.f;
    int nrows = t0;
    int t = 0;
#pragma unroll 2
    for (; t + 4 <= nrows; t += 4) {
        float k0 = Kb[(size_t)(t + 0) * PDIM];
        float k1 = Kb[(size_t)(t + 1) * PDIM];
        float k2 = Kb[(size_t)(t + 2) * PDIM];
        float k3 = Kb[(size_t)(t + 3) * PDIM];
        m0 = fmaxf(m0, k0); m1 = fmaxf(m1, k1);
        m2 = fmaxf(m2, k2); m3 = fmaxf(m3, k3);
        float e0 = __expf(k0), e1 = __expf(k1);
        float e2 = __expf(k2), e3 = __expf(k3);
        s0 += e0 * e0; s1 += e1 * e1; s2 += e2 * e2; s3 += e3 * e3;
    }
    // nrows is a multiple of 16, so no scalar remainder loop is needed
    float m = fmaxf(fmaxf(m0, m1), fmaxf(m2, m3));
    float s = (s0 + s1) + (s2 + s3);

    __shared__ bf16_t ek_t[CHS][PDIM + 4];   // [t_local][p]
    __shared__ float  dt[CHS][PDIM + 1];     // per-(t,p) den contribution

#pragma unroll
    for (int i = 0; i < CHS; ++i) {
        int tg = t0 + i;
        m = fmaxf(m, kq[i]);
        float ek = __expf(kq[i]);
        s += ek * ek;                         // inclusive running sum exp(2K)
        float w = __expf(qq_[i] - m);         // inclusive running max
        W[base + (size_t)tg * PDIM + p] = (bf16_t)w;
        U[base + (size_t)tg * PDIM + p] = (bf16_t)(vv[i] * ek);
        ek_t[i][p] = (bf16_t)ek;
        dt[i][p] = w * s;
    }
    __syncthreads();

    // den reduce: lane l -> t = l>>2, g = l&3; partial over p = 4*i+g
    {
        int tl = p >> 2, gg = p & 3;
        float d = 0.f;
#pragma unroll
        for (int i = 0; i < 16; ++i) d += dt[tl][i * 4 + gg];
        d += __shfl_xor(d, 1);
        d += __shfl_xor(d, 2);
        if (gg == 0) den[bh * TDIM + t0 + tl] = d;
    }

    // transposed Kft write
    {
        int hi = p >> 4, tl = p & 15;
#pragma unroll
        for (int it = 0; it < 16; ++it) {
            int q = it * 4 + hi;
            Kft[((size_t)bh * PDIM + q) * TDIM + t0 + tl] = ek_t[tl][q];
        }
    }
}

// ---------------------------------------------------------------------------
// B: per-(bh, 64-row tile) causal double matmul — LDS-staged + pipelined.
// (R5-verbatim: matched prediction, ~3 us.)
// 512 thr / 8 waves: wave = par*4 + sub. sub = 16-row substrip of the i-tile,
// par = kt parity. Each super-iteration stages TWO kt tiles (slots 0/1) into
// LDS once (coalesced 128B segments, shared by all waves), while the NEXT
// super-iteration's tiles are register-prefetched so global latency hides
// under the 32 MFMAs of compute. Ct (per-wave C round-trip) and Yred
// (cross-parity reduce) share one LDS buffer, barrier-ordered.
// grid = i*16 + bh (256 blocks); bh&7 spreads XCDs, 2 bh/XCD fits L2.
// ---------------------------------------------------------------------------
__global__ __launch_bounds__(512) void attn_kernel(
        const bf16_t* __restrict__ W, const bf16_t* __restrict__ U,
        const bf16_t* __restrict__ Kft, const float* __restrict__ den,
        float* __restrict__ out) {
    int bh  = blockIdx.x & 15;
    int i   = blockIdx.x >> 4;   // row tile index 0..15
    int tid = threadIdx.x;
    int wave = tid >> 6, lane = tid & 63;
    int lq = lane & 15, qd = lane >> 4;
    int sub = wave & 3;          // substrip: rows [16*sub, 16*sub+16) of tile
    int par = wave >> 2;         // kt parity handled by this wave
    int b = bh >> 3, h = bh & 7;

    __shared__ bf16_t Wt[64][72];
    __shared__ bf16_t Ut[2][64][72];
    __shared__ bf16_t Kt[2][64][72];
    __shared__ __align__(16) char ctyraw[8 * 16 * 72 * 2];  // Ct / Yred union
    __shared__ float denb[64];
    bf16_t (*Ct)[16][72]  = (bf16_t (*)[16][72])ctyraw;
    float  (*Yred)[16][68] = (float (*)[16][68])ctyraw;

    size_t base = (size_t)bh * TDIM * PDIM;
    size_t kftb = (size_t)bh * PDIM * TDIM;
    int row = tid >> 3, c8 = (tid & 7) << 3;   // staging coords: 1 int4/thread

    // ---- stage Wt + denb; prefetch tiles kt=0,1 (always in-bounds) ----
    int4 wfrag = *(const int4*)(W + base + (size_t)(i * 64 + row) * PDIM + c8);
    int4 pu0 = *(const int4*)(U + base + (size_t)(0 * 64 + row) * PDIM + c8);
    int4 pk0 = *(const int4*)(Kft + kftb + (size_t)row * TDIM + 0 * 64 + c8);
    int4 pu1 = *(const int4*)(U + base + (size_t)(1 * 64 + row) * PDIM + c8);
    int4 pk1 = *(const int4*)(Kft + kftb + (size_t)row * TDIM + 1 * 64 + c8);
    *(int4*)&Wt[row][c8] = wfrag;
    if (tid < 64) denb[tid] = den[bh * TDIM + i * 64 + tid];
    __syncthreads();

    // hoist this wave's W A-fragments (rows sub*16+lq of the i-tile)
    bf16x8 a0 = *(const bf16x8*)&Wt[sub * 16 + lq][qd * 8];
    bf16x8 a1 = *(const bf16x8*)&Wt[sub * 16 + lq][32 + qd * 8];

    floatx4 acc[4];
#pragma unroll
    for (int j = 0; j < 4; ++j) acc[j] = (floatx4){0.f, 0.f, 0.f, 0.f};

    int niter = (i >> 1) + 1;
    for (int kt2 = 0; kt2 < niter; ++kt2) {
        __syncthreads();   // previous compute done reading Ut/Kt
        *(int4*)&Ut[0][row][c8] = pu0;
        *(int4*)&Kt[0][row][c8] = pk0;
        *(int4*)&Ut[1][row][c8] = pu1;
        *(int4*)&Kt[1][row][c8] = pk1;
        // prefetch next super-iteration (loads fly under this one's compute)
        if (kt2 + 1 < niter) {
            int ktn = 2 * kt2 + 2;
            int ktn1 = ktn + 1 > 15 ? 15 : ktn + 1;
            pu0 = *(const int4*)(U + base + (size_t)(ktn * 64 + row) * PDIM + c8);
            pk0 = *(const int4*)(Kft + kftb + (size_t)row * TDIM + ktn * 64 + c8);
            pu1 = *(const int4*)(U + base + (size_t)(ktn1 * 64 + row) * PDIM + c8);
            pk1 = *(const int4*)(Kft + kftb + (size_t)row * TDIM + ktn1 * 64 + c8);
        }
        __syncthreads();   // LDS tiles ready

        int kt = 2 * kt2 + par;
        if (kt <= i) {     // wave-uniform
            // ---- phase 1: C[16 x 64] = W_sub . U_tile^T ----
            floatx4 cc[4];
#pragma unroll
            for (int j = 0; j < 4; ++j) {
                bf16x8 b0 = *(const bf16x8*)&Ut[par][j * 16 + lq][qd * 8];
                bf16x8 b1 = *(const bf16x8*)&Ut[par][j * 16 + lq][32 + qd * 8];
                floatx4 t = (floatx4){0.f, 0.f, 0.f, 0.f};
                t = mfma16(a0, b0, t);
                t = mfma16(a1, b1, t);
                cc[j] = t;
            }
            // ---- causal mask + C -> per-wave LDS (C/D: row=qd*4+r, col=lq)
            int trow0 = i * 64 + sub * 16;
#pragma unroll
            for (int j = 0; j < 4; ++j) {
#pragma unroll
                for (int r = 0; r < 4; ++r) {
                    float v = cc[j][r];
                    if (kt == i && (kt * 64 + j * 16 + lq) > (trow0 + qd * 4 + r))
                        v = 0.f;
                    Ct[wave][qd * 4 + r][j * 16 + lq] = (bf16_t)v;
                }
            }
            // same-wave write->read: compiler lgkmcnt, no barrier
            bf16x8 ca0 = *(const bf16x8*)&Ct[wave][lq][qd * 8];
            bf16x8 ca1 = *(const bf16x8*)&Ct[wave][lq][32 + qd * 8];
            // ---- phase 2: Y_sub += C . Kf_tile ----
#pragma unroll
            for (int j = 0; j < 4; ++j) {
                bf16x8 kb0 = *(const bf16x8*)&Kt[par][j * 16 + lq][qd * 8];
                bf16x8 kb1 = *(const bf16x8*)&Kt[par][j * 16 + lq][32 + qd * 8];
                acc[j] = mfma16(ca0, kb0, acc[j]);
                acc[j] = mfma16(ca1, kb1, acc[j]);
            }
        }
    }

    // ---- cross-parity reduce (Yred aliases Ct; barriers order it) ----
    __syncthreads();
    if (par == 1) {
#pragma unroll
        for (int j = 0; j < 4; ++j)
#pragma unroll
            for (int r = 0; r < 4; ++r)
                Yred[sub][qd * 4 + r][j * 16 + lq] = acc[j][r];
    }
    __syncthreads();
    if (par == 0) {
#pragma unroll
        for (int j = 0; j < 4; ++j) {
#pragma unroll
            for (int r = 0; r < 4; ++r) {
                int trow_l = sub * 16 + qd * 4 + r;
                int tg = i * 64 + trow_l;
                float y = acc[j][r] + Yred[sub][qd * 4 + r][j * 16 + lq];
                y = y / (denb[trow_l] + 1e-6f);
                out[((size_t)b * TDIM + tg) * (8 * PDIM) + h * PDIM + j * 16 + lq] = y;
            }
        }
    }
}

// ---------------------------------------------------------------------------
extern "C" void kernel_launch(void* const* d_in, const int* in_sizes, int n_in,
                              void* d_out, int out_size, void* d_ws, size_t ws_size,
                              hipStream_t stream) {
    const float* Q = (const float*)d_in[0];
    const float* K = (const float*)d_in[1];
    const float* V = (const float*)d_in[2];
    float* out = (float*)d_out;

    bf16_t* Wf   = (bf16_t*)d_ws;                       // 2 MB
    bf16_t* Uf   = Wf + (size_t)BHN * TDIM * PDIM;      // 2 MB
    bf16_t* Kft  = Uf + (size_t)BHN * TDIM * PDIM;      // 2 MB
    float*  den  = (float*)(Kft + (size_t)BHN * TDIM * PDIM);  // 64 KB

    scanfeat_kernel<<<BHN * NCH, 64, 0, stream>>>(Q, K, V, Wf, Uf, Kft, den);
    attn_kernel<<<256, 512, 0, stream>>>(Wf, Uf, Kft, den, out);
}

// Round 8
// 95.641 us; speedup vs baseline: 1.4826x; 1.0643x over previous
//
#include <hip/hip_runtime.h>
#include <hip/hip_bf16.h>

// Problem shape (fixed by setup_inputs): B=2, H=8, T=1024, P=64
#define TDIM 1024
#define PDIM 64
#define BHN  16     // B*H
#define SCH  8      // stats chunk size (rows)
#define NSC  128    // stats chunks per bh (NSC*SCH == TDIM)

typedef __bf16 bf16_t;
typedef bf16_t bf16x8 __attribute__((ext_vector_type(8)));
typedef float  floatx4 __attribute__((ext_vector_type(4)));

__device__ __forceinline__ floatx4 mfma16(bf16x8 a, bf16x8 b, floatx4 c) {
    return __builtin_amdgcn_mfma_f32_16x16x32_bf16(a, b, c, 0, 0, 0);
}

// ---------------------------------------------------------------------------
// A: per-(bh, 8-row chunk) stats: (max K, sum exp(2K)) per column p, stored
// interleaved as float2. grid = BHN*NSC = 2048 blocks of 64 thr -> 8 waves/CU.
// ---------------------------------------------------------------------------
__global__ __launch_bounds__(64) void stats_kernel(
        const float* __restrict__ K, float2* __restrict__ stats) {
    int bh = blockIdx.x >> 7;
    int c  = blockIdx.x & 127;
    int p  = threadIdx.x;
    const float* Kb = K + (size_t)bh * TDIM * PDIM + (size_t)c * SCH * PDIM + p;
    float k[SCH];
#pragma unroll
    for (int i = 0; i < SCH; ++i) k[i] = Kb[i * PDIM];
    float m = -INFINITY, s = 0.f;
#pragma unroll
    for (int i = 0; i < SCH; ++i) {
        m = fmaxf(m, k[i]);
        float e = __expf(k[i]);
        s += e * e;
    }
    stats[((size_t)(bh << 7) + c) * PDIM + p] = make_float2(m, s);
}

// ---------------------------------------------------------------------------
// B: fused feat+attn. Block = (bh, i-tile), 512 thr / 8 waves.
// Stage A (in-block feat): wave w scans tile rows [w*8, w*8+8): seeds per-
//   column (max, sum-exp2) from <=127 independent chunk-stat float2 loads,
//   then an 8-row serial scan -> W tile (LDS) + den (shfl-reduce). No global
//   W/U/Kft/den arrays at all (R7 lesson: never recompute O(T^2) prefixes;
//   R5 lesson: intermediates via global cost a dispatch + 6 MB round-trip).
// Stage B (K-loop, R5-proven shape): dual-slot staging now RECOMPUTES
//   U = bf16(V*exp(K)) and Kf^T = bf16(exp(K)) from register-prefetched
//   K/V float4 tiles (L2-hot: XCD = blockIdx%8 = bh%8, 2 bh/XCD).
//   Waves split kt by parity; per-wave Ct round-trip; Yred union epilogue.
// ---------------------------------------------------------------------------
__global__ __launch_bounds__(512) void featattn_kernel(
        const float* __restrict__ Q, const float* __restrict__ K,
        const float* __restrict__ V, const float2* __restrict__ stats,
        float* __restrict__ out) {
    int bh  = blockIdx.x & 15;
    int i   = blockIdx.x >> 4;   // row tile index 0..15
    int tid = threadIdx.x;
    int wave = tid >> 6, lane = tid & 63;
    int lq = lane & 15, qd = lane >> 4;
    int sub = wave & 3;          // substrip: rows [16*sub, 16*sub+16) of tile
    int par = wave >> 2;         // kt parity handled by this wave
    int b = bh >> 3, h = bh & 7;

    __shared__ bf16_t Wt[64][72];
    __shared__ bf16_t Ut[2][64][72];
    __shared__ bf16_t Kt[2][64][72];
    __shared__ __align__(16) char ctyraw[8 * 16 * 72 * 2];  // Ct / Yred union
    __shared__ float denb[64];
    bf16_t (*Ct)[16][72]  = (bf16_t (*)[16][72])ctyraw;
    float  (*Yred)[16][68] = (float (*)[16][68])ctyraw;

    size_t base = (size_t)bh * TDIM * PDIM;
    int trow = tid >> 3;            // staging: row within tile (0..63)
    int c0   = (tid & 7) << 3;      // staging: first of 8 columns

    // ---- issue K/V prefetch for tiles 0,1 first (fly under stage A) ----
    // tile indices 2*kt2+{0,1} never exceed 15, so addresses always valid.
    const float* Kst = K + base + (size_t)trow * PDIM + c0;
    const float* Vst = V + base + (size_t)trow * PDIM + c0;
    floatx4 pk0a = *(const floatx4*)(Kst);
    floatx4 pk0b = *(const floatx4*)(Kst + 4);
    floatx4 pv0a = *(const floatx4*)(Vst);
    floatx4 pv0b = *(const floatx4*)(Vst + 4);
    floatx4 pk1a = *(const floatx4*)(Kst + 64 * PDIM);
    floatx4 pk1b = *(const floatx4*)(Kst + 64 * PDIM + 4);
    floatx4 pv1a = *(const floatx4*)(Vst + 64 * PDIM);
    floatx4 pv1b = *(const floatx4*)(Vst + 64 * PDIM + 4);

    // ---- stage A: W tile + den for rows [i*64 + wave*8, +8) ----
    {
        int gchunk = 8 * i + wave;   // # of 8-row chunks before this strip
        const float2* st2 = stats + (size_t)(bh << 7) * PDIM + lane;
        float m0 = -INFINITY, m1 = -INFINITY, m2 = -INFINITY, m3 = -INFINITY;
        float s0 = 0.f, s1 = 0.f, s2 = 0.f, s3 = 0.f;
        int cc = 0;
        for (; cc + 4 <= gchunk; cc += 4) {
            float2 v0 = st2[(size_t)(cc + 0) * PDIM];
            float2 v1 = st2[(size_t)(cc + 1) * PDIM];
            float2 v2 = st2[(size_t)(cc + 2) * PDIM];
            float2 v3 = st2[(size_t)(cc + 3) * PDIM];
            m0 = fmaxf(m0, v0.x); s0 += v0.y;
            m1 = fmaxf(m1, v1.x); s1 += v1.y;
            m2 = fmaxf(m2, v2.x); s2 += v2.y;
            m3 = fmaxf(m3, v3.x); s3 += v3.y;
        }
        for (; cc < gchunk; ++cc) {
            float2 v = st2[(size_t)cc * PDIM];
            m0 = fmaxf(m0, v.x); s0 += v.y;
        }
        float m = fmaxf(fmaxf(m0, m1), fmaxf(m2, m3));
        float s = (s0 + s1) + (s2 + s3);

        int t0 = i * 64 + wave * 8;
        float kr[8], qr[8];
#pragma unroll
        for (int j = 0; j < 8; ++j) {
            kr[j] = K[base + (size_t)(t0 + j) * PDIM + lane];
            qr[j] = Q[base + (size_t)(t0 + j) * PDIM + lane];
        }
#pragma unroll
        for (int j = 0; j < 8; ++j) {
            m = fmaxf(m, kr[j]);
            float e = __expf(kr[j]);
            s += e * e;                       // inclusive running sum exp(2K)
            float wv = __expf(qr[j] - m);     // inclusive running max
            Wt[wave * 8 + j][lane] = (bf16_t)wv;
            float d = wv * s;
#pragma unroll
            for (int off = 32; off > 0; off >>= 1) d += __shfl_xor(d, off);
            if (lane == 0) denb[wave * 8 + j] = d;
        }
    }
    __syncthreads();

    // hoist this wave's W A-fragments
    bf16x8 a0 = *(const bf16x8*)&Wt[sub * 16 + lq][qd * 8];
    bf16x8 a1 = *(const bf16x8*)&Wt[sub * 16 + lq][32 + qd * 8];

    floatx4 acc[4];
#pragma unroll
    for (int j = 0; j < 4; ++j) acc[j] = (floatx4){0.f, 0.f, 0.f, 0.f};

    int niter = (i >> 1) + 1;
    for (int kt2 = 0; kt2 < niter; ++kt2) {
        __syncthreads();   // previous compute done reading Ut/Kt
        // ---- staging with fused recompute: U = bf16(V*expK), Kf^T = bf16(expK)
        {
            float kk[8] = {pk0a.x, pk0a.y, pk0a.z, pk0a.w,
                           pk0b.x, pk0b.y, pk0b.z, pk0b.w};
            float vv[8] = {pv0a.x, pv0a.y, pv0a.z, pv0a.w,
                           pv0b.x, pv0b.y, pv0b.z, pv0b.w};
            bf16x8 uv, kv;
#pragma unroll
            for (int j = 0; j < 8; ++j) {
                float e = __expf(kk[j]);
                kv[j] = (bf16_t)e;
                uv[j] = (bf16_t)(vv[j] * e);
            }
            *(bf16x8*)&Ut[0][trow][c0] = uv;
#pragma unroll
            for (int j = 0; j < 8; ++j) Kt[0][c0 + j][trow] = kv[j];
        }
        {
            float kk[8] = {pk1a.x, pk1a.y, pk1a.z, pk1a.w,
                           pk1b.x, pk1b.y, pk1b.z, pk1b.w};
            float vv[8] = {pv1a.x, pv1a.y, pv1a.z, pv1a.w,
                           pv1b.x, pv1b.y, pv1b.z, pv1b.w};
            bf16x8 uv, kv;
#pragma unroll
            for (int j = 0; j < 8; ++j) {
                float e = __expf(kk[j]);
                kv[j] = (bf16_t)e;
                uv[j] = (bf16_t)(vv[j] * e);
            }
            *(bf16x8*)&Ut[1][trow][c0] = uv;
#pragma unroll
            for (int j = 0; j < 8; ++j) Kt[1][c0 + j][trow] = kv[j];
        }
        // ---- prefetch next super-iteration's K/V tiles ----
        if (kt2 + 1 < niter) {
            const float* Kn = Kst + (size_t)(2 * kt2 + 2) * 64 * PDIM;
            const float* Vn = Vst + (size_t)(2 * kt2 + 2) * 64 * PDIM;
            pk0a = *(const floatx4*)(Kn);
            pk0b = *(const floatx4*)(Kn + 4);
            pv0a = *(const floatx4*)(Vn);
            pv0b = *(const floatx4*)(Vn + 4);
            pk1a = *(const floatx4*)(Kn + 64 * PDIM);
            pk1b = *(const floatx4*)(Kn + 64 * PDIM + 4);
            pv1a = *(const floatx4*)(Vn + 64 * PDIM);
            pv1b = *(const floatx4*)(Vn + 64 * PDIM + 4);
        }
        __syncthreads();   // LDS tiles ready

        int kt = 2 * kt2 + par;
        if (kt <= i) {     // wave-uniform
            // ---- phase 1: C[16 x 64] = W_sub . U_tile^T ----
            floatx4 cc4[4];
#pragma unroll
            for (int j = 0; j < 4; ++j) {
                bf16x8 b0 = *(const bf16x8*)&Ut[par][j * 16 + lq][qd * 8];
                bf16x8 b1 = *(const bf16x8*)&Ut[par][j * 16 + lq][32 + qd * 8];
                floatx4 t = (floatx4){0.f, 0.f, 0.f, 0.f};
                t = mfma16(a0, b0, t);
                t = mfma16(a1, b1, t);
                cc4[j] = t;
            }
            // ---- causal mask + C -> per-wave LDS (C/D: row=qd*4+r, col=lq)
            int trow0 = i * 64 + sub * 16;
#pragma unroll
            for (int j = 0; j < 4; ++j) {
#pragma unroll
                for (int r = 0; r < 4; ++r) {
                    float v = cc4[j][r];
                    if (kt == i && (kt * 64 + j * 16 + lq) > (trow0 + qd * 4 + r))
                        v = 0.f;
                    Ct[wave][qd * 4 + r][j * 16 + lq] = (bf16_t)v;
                }
            }
            // same-wave write->read: compiler lgkmcnt, no barrier
            bf16x8 ca0 = *(const bf16x8*)&Ct[wave][lq][qd * 8];
            bf16x8 ca1 = *(const bf16x8*)&Ct[wave][lq][32 + qd * 8];
            // ---- phase 2: Y_sub += C . Kf_tile ----
#pragma unroll
            for (int j = 0; j < 4; ++j) {
                bf16x8 kb0 = *(const bf16x8*)&Kt[par][j * 16 + lq][qd * 8];
                bf16x8 kb1 = *(const bf16x8*)&Kt[par][j * 16 + lq][32 + qd * 8];
                acc[j] = mfma16(ca0, kb0, acc[j]);
                acc[j] = mfma16(ca1, kb1, acc[j]);
            }
        }
    }

    // ---- cross-parity reduce (Yred aliases Ct; barriers order it) ----
    __syncthreads();
    if (par == 1) {
#pragma unroll
        for (int j = 0; j < 4; ++j)
#pragma unroll
            for (int r = 0; r < 4; ++r)
                Yred[sub][qd * 4 + r][j * 16 + lq] = acc[j][r];
    }
    __syncthreads();
    if (par == 0) {
#pragma unroll
        for (int j = 0; j < 4; ++j) {
#pragma unroll
            for (int r = 0; r < 4; ++r) {
                int trow_l = sub * 16 + qd * 4 + r;
                int tg = i * 64 + trow_l;
                float y = acc[j][r] + Yred[sub][qd * 4 + r][j * 16 + lq];
                y = y / (denb[trow_l] + 1e-6f);
                out[((size_t)b * TDIM + tg) * (8 * PDIM) + h * PDIM + j * 16 + lq] = y;
            }
        }
    }
}

// ---------------------------------------------------------------------------
extern "C" void kernel_launch(void* const* d_in, const int* in_sizes, int n_in,
                              void* d_out, int out_size, void* d_ws, size_t ws_size,
                              hipStream_t stream) {
    const float* Q = (const float*)d_in[0];
    const float* K = (const float*)d_in[1];
    const float* V = (const float*)d_in[2];
    float* out = (float*)d_out;

    float2* stats = (float2*)d_ws;   // BHN*NSC*PDIM float2 = 1 MB

    stats_kernel<<<BHN * NSC, 64, 0, stream>>>(K, stats);
    featattn_kernel<<<256, 512, 0, stream>>>(Q, K, V, stats, out);
}

// Round 9
// 88.348 us; speedup vs baseline: 1.6050x; 1.0826x over previous
//
#include <hip/hip_runtime.h>
#include <hip/hip_bf16.h>

// Problem shape (fixed by setup_inputs): B=2, H=8, T=1024, P=64
#define TDIM 1024
#define PDIM 64
#define BHN  16     // B*H
#define SCH  8      // stats chunk size (rows)
#define NSC  128    // stats chunks per bh (NSC*SCH == TDIM)

typedef __bf16 bf16_t;
typedef bf16_t bf16x8 __attribute__((ext_vector_type(8)));
typedef float  floatx4 __attribute__((ext_vector_type(4)));

__device__ __forceinline__ floatx4 mfma16(bf16x8 a, bf16x8 b, floatx4 c) {
    return __builtin_amdgcn_mfma_f32_16x16x32_bf16(a, b, c, 0, 0, 0);
}

// ---------------------------------------------------------------------------
// prep: NO scan — everything here is elementwise or a local transpose.
//   stats[bh][c8][p] = (max K, sum exp2K) over 8-row chunk c8   (float2)
//   U[bh][t][p]      = bf16( V * exp(K) )                        (natural)
//   Kft[bh][q][t]    = bf16( exp(K[t][q]) )   (transposed via padded LDS
//                      tile + coalesced global write — R5-proven; R8's
//                      in-consumer LDS transpose hit 16-way bank conflicts)
// grid = BHN*64 blocks (16-row tiles) of 64 thr (lane = p) -> 4 waves/CU.
// ---------------------------------------------------------------------------
__global__ __launch_bounds__(64) void prep_kernel(
        const float* __restrict__ K, const float* __restrict__ V,
        bf16_t* __restrict__ U, bf16_t* __restrict__ Kft,
        float2* __restrict__ stats) {
    int bh = blockIdx.x >> 6;
    int c  = blockIdx.x & 63;     // 16-row tile index
    int p  = threadIdx.x;
    size_t base = (size_t)bh * TDIM * PDIM;
    int t0 = c * 16;

    float kq[16], vv[16];
#pragma unroll
    for (int i = 0; i < 16; ++i) {
        kq[i] = K[base + (size_t)(t0 + i) * PDIM + p];
        vv[i] = V[base + (size_t)(t0 + i) * PDIM + p];
    }

    __shared__ bf16_t ek_t[16][PDIM + 4];
    float m0 = -INFINITY, s0 = 0.f, m1 = -INFINITY, s1 = 0.f;
#pragma unroll
    for (int i = 0; i < 16; ++i) {
        float e = __expf(kq[i]);
        if (i < 8) { m0 = fmaxf(m0, kq[i]); s0 += e * e; }
        else       { m1 = fmaxf(m1, kq[i]); s1 += e * e; }
        U[base + (size_t)(t0 + i) * PDIM + p] = (bf16_t)(vv[i] * e);
        ek_t[i][p] = (bf16_t)e;
    }
    stats[((size_t)(bh << 7) + 2 * c + 0) * PDIM + p] = make_float2(m0, s0);
    stats[((size_t)(bh << 7) + 2 * c + 1) * PDIM + p] = make_float2(m1, s1);
    __syncthreads();

    // transposed write: lanes (hi=p>>4, tl=p&15); 4 q-rows per iteration
    int hi = p >> 4, tl = p & 15;
#pragma unroll
    for (int it = 0; it < 16; ++it) {
        int q = it * 4 + hi;
        Kft[((size_t)bh * PDIM + q) * TDIM + t0 + tl] = ek_t[tl][q];
    }
}

// ---------------------------------------------------------------------------
// featattn: R8's in-block stage A (W/den — the only scan-dependent pieces)
// + R5's PROVEN K-loop (bf16 U/Kft int4 staging, dual slots, register
// prefetch, parity-split waves, per-wave Ct round-trip, Yred epilogue).
// Block = (bh, i-tile), 512 thr / 8 waves; wave = par*4 + sub.
// grid = i*16 + bh (256 blocks); bh&7 spreads XCDs, 2 bh/XCD fits L2.
// ---------------------------------------------------------------------------
__global__ __launch_bounds__(512) void featattn_kernel(
        const float* __restrict__ Q, const float* __restrict__ K,
        const bf16_t* __restrict__ U, const bf16_t* __restrict__ Kft,
        const float2* __restrict__ stats, float* __restrict__ out) {
    int bh  = blockIdx.x & 15;
    int i   = blockIdx.x >> 4;   // row tile index 0..15
    int tid = threadIdx.x;
    int wave = tid >> 6, lane = tid & 63;
    int lq = lane & 15, qd = lane >> 4;
    int sub = wave & 3;          // substrip: rows [16*sub, 16*sub+16) of tile
    int par = wave >> 2;         // kt parity handled by this wave
    int b = bh >> 3, h = bh & 7;

    __shared__ bf16_t Wt[64][72];
    __shared__ bf16_t Ut[2][64][72];
    __shared__ bf16_t Kt[2][64][72];
    __shared__ __align__(16) char ctyraw[8 * 16 * 72 * 2];  // Ct / Yred union
    __shared__ float denb[64];
    bf16_t (*Ct)[16][72]  = (bf16_t (*)[16][72])ctyraw;
    float  (*Yred)[16][68] = (float (*)[16][68])ctyraw;

    size_t base = (size_t)bh * TDIM * PDIM;
    size_t kftb = (size_t)bh * PDIM * TDIM;
    int row = tid >> 3, c8 = (tid & 7) << 3;   // staging coords: 1 int4/thread

    // ---- prefetch tiles kt=0,1 (always in-bounds; fly under stage A) ----
    int4 pu0 = *(const int4*)(U + base + (size_t)(0 * 64 + row) * PDIM + c8);
    int4 pk0 = *(const int4*)(Kft + kftb + (size_t)row * TDIM + 0 * 64 + c8);
    int4 pu1 = *(const int4*)(U + base + (size_t)(1 * 64 + row) * PDIM + c8);
    int4 pk1 = *(const int4*)(Kft + kftb + (size_t)row * TDIM + 1 * 64 + c8);

    // ---- stage A: W tile + den for rows [i*64 + wave*8, +8) ----
    {
        int gchunk = 8 * i + wave;   // # of 8-row chunks before this strip
        const float2* st2 = stats + (size_t)(bh << 7) * PDIM + lane;
        float m0 = -INFINITY, m1 = -INFINITY, m2 = -INFINITY, m3 = -INFINITY;
        float s0 = 0.f, s1 = 0.f, s2 = 0.f, s3 = 0.f;
        int cc = 0;
        for (; cc + 4 <= gchunk; cc += 4) {
            float2 v0 = st2[(size_t)(cc + 0) * PDIM];
            float2 v1 = st2[(size_t)(cc + 1) * PDIM];
            float2 v2 = st2[(size_t)(cc + 2) * PDIM];
            float2 v3 = st2[(size_t)(cc + 3) * PDIM];
            m0 = fmaxf(m0, v0.x); s0 += v0.y;
            m1 = fmaxf(m1, v1.x); s1 += v1.y;
            m2 = fmaxf(m2, v2.x); s2 += v2.y;
            m3 = fmaxf(m3, v3.x); s3 += v3.y;
        }
        for (; cc < gchunk; ++cc) {
            float2 v = st2[(size_t)cc * PDIM];
            m0 = fmaxf(m0, v.x); s0 += v.y;
        }
        float m = fmaxf(fmaxf(m0, m1), fmaxf(m2, m3));
        float s = (s0 + s1) + (s2 + s3);

        int t0 = i * 64 + wave * 8;
        float kr[8], qr[8], d[8];
#pragma unroll
        for (int j = 0; j < 8; ++j) {
            kr[j] = K[base + (size_t)(t0 + j) * PDIM + lane];
            qr[j] = Q[base + (size_t)(t0 + j) * PDIM + lane];
        }
#pragma unroll
        for (int j = 0; j < 8; ++j) {
            m = fmaxf(m, kr[j]);
            float e = __expf(kr[j]);
            s += e * e;                       // inclusive running sum exp(2K)
            float wv = __expf(qr[j] - m);     // inclusive running max
            Wt[wave * 8 + j][lane] = (bf16_t)wv;
            d[j] = wv * s;
        }
        // post-scan reduce: 8 independent butterflies (ILP), not in-loop
#pragma unroll
        for (int off = 32; off > 0; off >>= 1)
#pragma unroll
            for (int j = 0; j < 8; ++j) d[j] += __shfl_xor(d[j], off);
        if (lane == 0) {
#pragma unroll
            for (int j = 0; j < 8; ++j) denb[wave * 8 + j] = d[j];
        }
    }
    __syncthreads();

    // hoist this wave's W A-fragments
    bf16x8 a0 = *(const bf16x8*)&Wt[sub * 16 + lq][qd * 8];
    bf16x8 a1 = *(const bf16x8*)&Wt[sub * 16 + lq][32 + qd * 8];

    floatx4 acc[4];
#pragma unroll
    for (int j = 0; j < 4; ++j) acc[j] = (floatx4){0.f, 0.f, 0.f, 0.f};

    int niter = (i >> 1) + 1;
    for (int kt2 = 0; kt2 < niter; ++kt2) {
        __syncthreads();   // previous compute done reading Ut/Kt
        *(int4*)&Ut[0][row][c8] = pu0;
        *(int4*)&Kt[0][row][c8] = pk0;
        *(int4*)&Ut[1][row][c8] = pu1;
        *(int4*)&Kt[1][row][c8] = pk1;
        // prefetch next super-iteration (loads fly under this one's compute)
        if (kt2 + 1 < niter) {
            int ktn = 2 * kt2 + 2;
            int ktn1 = ktn + 1 > 15 ? 15 : ktn + 1;
            pu0 = *(const int4*)(U + base + (size_t)(ktn * 64 + row) * PDIM + c8);
            pk0 = *(const int4*)(Kft + kftb + (size_t)row * TDIM + ktn * 64 + c8);
            pu1 = *(const int4*)(U + base + (size_t)(ktn1 * 64 + row) * PDIM + c8);
            pk1 = *(const int4*)(Kft + kftb + (size_t)row * TDIM + ktn1 * 64 + c8);
        }
        __syncthreads();   // LDS tiles ready

        int kt = 2 * kt2 + par;
        if (kt <= i) {     // wave-uniform
            // ---- phase 1: C[16 x 64] = W_sub . U_tile^T ----
            floatx4 cc4[4];
#pragma unroll
            for (int j = 0; j < 4; ++j) {
                bf16x8 b0 = *(const bf16x8*)&Ut[par][j * 16 + lq][qd * 8];
                bf16x8 b1 = *(const bf16x8*)&Ut[par][j * 16 + lq][32 + qd * 8];
                floatx4 t = (floatx4){0.f, 0.f, 0.f, 0.f};
                t = mfma16(a0, b0, t);
                t = mfma16(a1, b1, t);
                cc4[j] = t;
            }
            // ---- causal mask + C -> per-wave LDS (C/D: row=qd*4+r, col=lq)
            int trow0 = i * 64 + sub * 16;
#pragma unroll
            for (int j = 0; j < 4; ++j) {
#pragma unroll
                for (int r = 0; r < 4; ++r) {
                    float v = cc4[j][r];
                    if (kt == i && (kt * 64 + j * 16 + lq) > (trow0 + qd * 4 + r))
                        v = 0.f;
                    Ct[wave][qd * 4 + r][j * 16 + lq] = (bf16_t)v;
                }
            }
            // same-wave write->read: compiler lgkmcnt, no barrier
            bf16x8 ca0 = *(const bf16x8*)&Ct[wave][lq][qd * 8];
            bf16x8 ca1 = *(const bf16x8*)&Ct[wave][lq][32 + qd * 8];
            // ---- phase 2: Y_sub += C . Kf_tile ----
#pragma unroll
            for (int j = 0; j < 4; ++j) {
                bf16x8 kb0 = *(const bf16x8*)&Kt[par][j * 16 + lq][qd * 8];
                bf16x8 kb1 = *(const bf16x8*)&Kt[par][j * 16 + lq][32 + qd * 8];
                acc[j] = mfma16(ca0, kb0, acc[j]);
                acc[j] = mfma16(ca1, kb1, acc[j]);
            }
        }
    }

    // ---- cross-parity reduce (Yred aliases Ct; barriers order it) ----
    __syncthreads();
    if (par == 1) {
#pragma unroll
        for (int j = 0; j < 4; ++j)
#pragma unroll
            for (int r = 0; r < 4; ++r)
                Yred[sub][qd * 4 + r][j * 16 + lq] = acc[j][r];
    }
    __syncthreads();
    if (par == 0) {
#pragma unroll
        for (int j = 0; j < 4; ++j) {
#pragma unroll
            for (int r = 0; r < 4; ++r) {
                int trow_l = sub * 16 + qd * 4 + r;
                int tg = i * 64 + trow_l;
                float y = acc[j][r] + Yred[sub][qd * 4 + r][j * 16 + lq];
                y = y / (denb[trow_l] + 1e-6f);
                out[((size_t)b * TDIM + tg) * (8 * PDIM) + h * PDIM + j * 16 + lq] = y;
            }
        }
    }
}

// ---------------------------------------------------------------------------
extern "C" void kernel_launch(void* const* d_in, const int* in_sizes, int n_in,
                              void* d_out, int out_size, void* d_ws, size_t ws_size,
                              hipStream_t stream) {
    const float* Q = (const float*)d_in[0];
    const float* K = (const float*)d_in[1];
    const float* V = (const float*)d_in[2];
    float* out = (float*)d_out;

    bf16_t* Uf   = (bf16_t*)d_ws;                            // 2 MB
    bf16_t* Kft  = Uf + (size_t)BHN * TDIM * PDIM;           // 2 MB
    float2* stats = (float2*)(Kft + (size_t)BHN * TDIM * PDIM);  // 1 MB

    prep_kernel<<<BHN * 64, 64, 0, stream>>>(K, V, Uf, Kft, stats);
    featattn_kernel<<<256, 512, 0, stream>>>(Q, K, Uf, Kft, stats, out);
}

// Round 10
// 84.501 us; speedup vs baseline: 1.6780x; 1.0455x over previous
//
#include <hip/hip_runtime.h>
#include <hip/hip_bf16.h>

// Problem shape (fixed by setup_inputs): B=2, H=8, T=1024, P=64
#define TDIM 1024
#define PDIM 64
#define BHN  16     // B*H
#define SCH  8      // stats chunk size (rows)
#define NSC  128    // stats chunks per bh (NSC*SCH == TDIM)

typedef __bf16 bf16_t;
typedef bf16_t bf16x8 __attribute__((ext_vector_type(8)));
typedef float  floatx4 __attribute__((ext_vector_type(4)));

__device__ __forceinline__ floatx4 mfma16(bf16x8 a, bf16x8 b, floatx4 c) {
    return __builtin_amdgcn_mfma_f32_16x16x32_bf16(a, b, c, 0, 0, 0);
}

// ---------------------------------------------------------------------------
// prep: NO scan — everything here is elementwise or a local transpose.
//   stats[bh][c8][p] = (max K, sum exp2K) over 8-row chunk c8   (float2)
//   U[bh][t][p]      = bf16( V * exp(K) )                        (natural)
//   Kft[bh][q][t]    = bf16( exp(K[t][q]) )   (transposed via padded LDS
//                      tile + coalesced global write)
// grid = BHN*64 blocks (16-row tiles) of 64 thr (lane = p) -> 4 waves/CU.
// ---------------------------------------------------------------------------
__global__ __launch_bounds__(64) void prep_kernel(
        const float* __restrict__ K, const float* __restrict__ V,
        bf16_t* __restrict__ U, bf16_t* __restrict__ Kft,
        float2* __restrict__ stats) {
    int bh = blockIdx.x >> 6;
    int c  = blockIdx.x & 63;     // 16-row tile index
    int p  = threadIdx.x;
    size_t base = (size_t)bh * TDIM * PDIM;
    int t0 = c * 16;

    float kq[16], vv[16];
#pragma unroll
    for (int i = 0; i < 16; ++i) {
        kq[i] = K[base + (size_t)(t0 + i) * PDIM + p];
        vv[i] = V[base + (size_t)(t0 + i) * PDIM + p];
    }

    __shared__ bf16_t ek_t[16][PDIM + 4];
    float m0 = -INFINITY, s0 = 0.f, m1 = -INFINITY, s1 = 0.f;
#pragma unroll
    for (int i = 0; i < 16; ++i) {
        float e = __expf(kq[i]);
        if (i < 8) { m0 = fmaxf(m0, kq[i]); s0 += e * e; }
        else       { m1 = fmaxf(m1, kq[i]); s1 += e * e; }
        U[base + (size_t)(t0 + i) * PDIM + p] = (bf16_t)(vv[i] * e);
        ek_t[i][p] = (bf16_t)e;
    }
    stats[((size_t)(bh << 7) + 2 * c + 0) * PDIM + p] = make_float2(m0, s0);
    stats[((size_t)(bh << 7) + 2 * c + 1) * PDIM + p] = make_float2(m1, s1);
    __syncthreads();

    // transposed write: lanes (hi=p>>4, tl=p&15); 4 q-rows per iteration
    int hi = p >> 4, tl = p & 15;
#pragma unroll
    for (int it = 0; it < 16; ++it) {
        int q = it * 4 + hi;
        Kft[((size_t)bh * PDIM + q) * TDIM + t0 + tl] = ek_t[tl][q];
    }
}

// ---------------------------------------------------------------------------
// featattn: in-block stage A (W/den — the only scan-dependent pieces) with a
// COOPERATIVE prefix (R9 lesson: the per-wave 127-chunk chain was ~2.7 us of
// serial L2 latency at 1 block/CU; waves share [0,8i), so reduce it jointly:
// thread (wave,lane) reduces residue class {c=wave mod 8} with 4-way split
// accumulators -> depth ~4 L2 rounds; partials via LDS; per-wave boundary
// adds <=7 chunks) + R5's PROVEN K-loop (bf16 U/Kft int4 staging, dual
// slots, register prefetch, parity-split waves, Ct round-trip, Yred).
// Block = (bh, i-tile), 512 thr / 8 waves; wave = par*4 + sub.
// grid = i*16 + bh (256 blocks); bh&7 spreads XCDs, 2 bh/XCD fits L2.
// ---------------------------------------------------------------------------
__global__ __launch_bounds__(512) void featattn_kernel(
        const float* __restrict__ Q, const float* __restrict__ K,
        const bf16_t* __restrict__ U, const bf16_t* __restrict__ Kft,
        const float2* __restrict__ stats, float* __restrict__ out) {
    int bh  = blockIdx.x & 15;
    int i   = blockIdx.x >> 4;   // row tile index 0..15
    int tid = threadIdx.x;
    int wave = tid >> 6, lane = tid & 63;
    int lq = lane & 15, qd = lane >> 4;
    int sub = wave & 3;          // substrip: rows [16*sub, 16*sub+16) of tile
    int par = wave >> 2;         // kt parity handled by this wave
    int b = bh >> 3, h = bh & 7;

    __shared__ bf16_t Wt[64][72];
    __shared__ bf16_t Ut[2][64][72];
    __shared__ bf16_t Kt[2][64][72];
    __shared__ __align__(16) char ctyraw[8 * 16 * 72 * 2];  // Ct/Yred/Pt union
    __shared__ float denb[64];
    bf16_t (*Ct)[16][72]  = (bf16_t (*)[16][72])ctyraw;
    float  (*Yred)[16][68] = (float (*)[16][68])ctyraw;
    float2 (*Pt)[64]       = (float2 (*)[64])ctyraw;   // stage-A partials 4KB

    size_t base = (size_t)bh * TDIM * PDIM;
    size_t kftb = (size_t)bh * PDIM * TDIM;
    int row = tid >> 3, c8 = (tid & 7) << 3;   // staging coords: 1 int4/thread

    // ---- prefetch tiles kt=0,1 (always in-bounds; fly under stage A) ----
    int4 pu0 = *(const int4*)(U + base + (size_t)(0 * 64 + row) * PDIM + c8);
    int4 pk0 = *(const int4*)(Kft + kftb + (size_t)row * TDIM + 0 * 64 + c8);
    int4 pu1 = *(const int4*)(U + base + (size_t)(1 * 64 + row) * PDIM + c8);
    int4 pk1 = *(const int4*)(Kft + kftb + (size_t)row * TDIM + 1 * 64 + c8);

    // ---- stage A: W tile + den for rows [i*64 + wave*8, +8) ----
    {
        int t0 = i * 64 + wave * 8;
        // own-row loads first: independent, fly under the stats reduction
        float kr[8], qr[8];
#pragma unroll
        for (int j = 0; j < 8; ++j) {
            kr[j] = K[base + (size_t)(t0 + j) * PDIM + lane];
            qr[j] = Q[base + (size_t)(t0 + j) * PDIM + lane];
        }

        // cooperative partial reduce over chunks [0, 8i):
        // thread (wave,lane) handles residue class {cc = wave mod 8}, col=lane
        const float2* st2 = stats + (size_t)(bh << 7) * PDIM + lane;
        int lim = 8 * i;
        float pm0 = -INFINITY, pm1 = -INFINITY, pm2 = -INFINITY, pm3 = -INFINITY;
        float ps0 = 0.f, ps1 = 0.f, ps2 = 0.f, ps3 = 0.f;
        int cc = wave;
        for (; cc + 24 < lim; cc += 32) {   // 4-way split: depth ~4 L2 rounds
            float2 v0 = st2[(size_t)(cc +  0) * PDIM];
            float2 v1 = st2[(size_t)(cc +  8) * PDIM];
            float2 v2 = st2[(size_t)(cc + 16) * PDIM];
            float2 v3 = st2[(size_t)(cc + 24) * PDIM];
            pm0 = fmaxf(pm0, v0.x); ps0 += v0.y;
            pm1 = fmaxf(pm1, v1.x); ps1 += v1.y;
            pm2 = fmaxf(pm2, v2.x); ps2 += v2.y;
            pm3 = fmaxf(pm3, v3.x); ps3 += v3.y;
        }
        for (; cc < lim; cc += 8) {
            float2 v = st2[(size_t)cc * PDIM];
            pm0 = fmaxf(pm0, v.x); ps0 += v.y;
        }
        Pt[wave][lane] = make_float2(fmaxf(fmaxf(pm0, pm1), fmaxf(pm2, pm3)),
                                     (ps0 + ps1) + (ps2 + ps3));
        __syncthreads();

        float m = -INFINITY, s = 0.f;
#pragma unroll
        for (int g = 0; g < 8; ++g) {
            float2 v = Pt[g][lane];
            m = fmaxf(m, v.x); s += v.y;
        }
        // boundary chunks [8i, 8i+wave): <=7 independent loads
        for (int bc = lim; bc < lim + wave; ++bc) {
            float2 v = st2[(size_t)bc * PDIM];
            m = fmaxf(m, v.x); s += v.y;
        }

        // 8-row seeded scan
        float d[8];
#pragma unroll
        for (int j = 0; j < 8; ++j) {
            m = fmaxf(m, kr[j]);
            float e = __expf(kr[j]);
            s += e * e;                       // inclusive running sum exp(2K)
            float wv = __expf(qr[j] - m);     // inclusive running max
            Wt[wave * 8 + j][lane] = (bf16_t)wv;
            d[j] = wv * s;
        }
        // post-scan reduce: 8 independent butterflies (ILP), not in-loop
#pragma unroll
        for (int off = 32; off > 0; off >>= 1)
#pragma unroll
            for (int j = 0; j < 8; ++j) d[j] += __shfl_xor(d[j], off);
        if (lane == 0) {
#pragma unroll
            for (int j = 0; j < 8; ++j) denb[wave * 8 + j] = d[j];
        }
    }
    __syncthreads();   // Wt/denb ready; Pt region free (reused as Ct)

    // hoist this wave's W A-fragments
    bf16x8 a0 = *(const bf16x8*)&Wt[sub * 16 + lq][qd * 8];
    bf16x8 a1 = *(const bf16x8*)&Wt[sub * 16 + lq][32 + qd * 8];

    floatx4 acc[4];
#pragma unroll
    for (int j = 0; j < 4; ++j) acc[j] = (floatx4){0.f, 0.f, 0.f, 0.f};

    int niter = (i >> 1) + 1;
    for (int kt2 = 0; kt2 < niter; ++kt2) {
        __syncthreads();   // previous compute done reading Ut/Kt
        *(int4*)&Ut[0][row][c8] = pu0;
        *(int4*)&Kt[0][row][c8] = pk0;
        *(int4*)&Ut[1][row][c8] = pu1;
        *(int4*)&Kt[1][row][c8] = pk1;
        // prefetch next super-iteration (loads fly under this one's compute)
        if (kt2 + 1 < niter) {
            int ktn = 2 * kt2 + 2;
            int ktn1 = ktn + 1 > 15 ? 15 : ktn + 1;
            pu0 = *(const int4*)(U + base + (size_t)(ktn * 64 + row) * PDIM + c8);
            pk0 = *(const int4*)(Kft + kftb + (size_t)row * TDIM + ktn * 64 + c8);
            pu1 = *(const int4*)(U + base + (size_t)(ktn1 * 64 + row) * PDIM + c8);
            pk1 = *(const int4*)(Kft + kftb + (size_t)row * TDIM + ktn1 * 64 + c8);
        }
        __syncthreads();   // LDS tiles ready

        int kt = 2 * kt2 + par;
        if (kt <= i) {     // wave-uniform
            // ---- phase 1: C[16 x 64] = W_sub . U_tile^T ----
            floatx4 cc4[4];
#pragma unroll
            for (int j = 0; j < 4; ++j) {
                bf16x8 b0 = *(const bf16x8*)&Ut[par][j * 16 + lq][qd * 8];
                bf16x8 b1 = *(const bf16x8*)&Ut[par][j * 16 + lq][32 + qd * 8];
                floatx4 t = (floatx4){0.f, 0.f, 0.f, 0.f};
                t = mfma16(a0, b0, t);
                t = mfma16(a1, b1, t);
                cc4[j] = t;
            }
            // ---- causal mask + C -> per-wave LDS (C/D: row=qd*4+r, col=lq)
            int trow0 = i * 64 + sub * 16;
#pragma unroll
            for (int j = 0; j < 4; ++j) {
#pragma unroll
                for (int r = 0; r < 4; ++r) {
                    float v = cc4[j][r];
                    if (kt == i && (kt * 64 + j * 16 + lq) > (trow0 + qd * 4 + r))
                        v = 0.f;
                    Ct[wave][qd * 4 + r][j * 16 + lq] = (bf16_t)v;
                }
            }
            // same-wave write->read: compiler lgkmcnt, no barrier
            bf16x8 ca0 = *(const bf16x8*)&Ct[wave][lq][qd * 8];
            bf16x8 ca1 = *(const bf16x8*)&Ct[wave][lq][32 + qd * 8];
            // ---- phase 2: Y_sub += C . Kf_tile ----
#pragma unroll
            for (int j = 0; j < 4; ++j) {
                bf16x8 kb0 = *(const bf16x8*)&Kt[par][j * 16 + lq][qd * 8];
                bf16x8 kb1 = *(const bf16x8*)&Kt[par][j * 16 + lq][32 + qd * 8];
                acc[j] = mfma16(ca0, kb0, acc[j]);
                acc[j] = mfma16(ca1, kb1, acc[j]);
            }
        }
    }

    // ---- cross-parity reduce (Yred aliases Ct; barriers order it) ----
    __syncthreads();
    if (par == 1) {
#pragma unroll
        for (int j = 0; j < 4; ++j)
#pragma unroll
            for (int r = 0; r < 4; ++r)
                Yred[sub][qd * 4 + r][j * 16 + lq] = acc[j][r];
    }
    __syncthreads();
    if (par == 0) {
#pragma unroll
        for (int j = 0; j < 4; ++j) {
#pragma unroll
            for (int r = 0; r < 4; ++r) {
                int trow_l = sub * 16 + qd * 4 + r;
                int tg = i * 64 + trow_l;
                float y = acc[j][r] + Yred[sub][qd * 4 + r][j * 16 + lq];
                y = y / (denb[trow_l] + 1e-6f);
                out[((size_t)b * TDIM + tg) * (8 * PDIM) + h * PDIM + j * 16 + lq] = y;
            }
        }
    }
}

// ---------------------------------------------------------------------------
extern "C" void kernel_launch(void* const* d_in, const int* in_sizes, int n_in,
                              void* d_out, int out_size, void* d_ws, size_t ws_size,
                              hipStream_t stream) {
    const float* Q = (const float*)d_in[0];
    const float* K = (const float*)d_in[1];
    const float* V = (const float*)d_in[2];
    float* out = (float*)d_out;

    bf16_t* Uf   = (bf16_t*)d_ws;                            // 2 MB
    bf16_t* Kft  = Uf + (size_t)BHN * TDIM * PDIM;           // 2 MB
    float2* stats = (float2*)(Kft + (size_t)BHN * TDIM * PDIM);  // 1 MB

    prep_kernel<<<BHN * 64, 64, 0, stream>>>(K, V, Uf, Kft, stats);
    featattn_kernel<<<256, 512, 0, stream>>>(Q, K, Uf, Kft, stats, out);
}